// Round 4
// baseline (491.415 us; speedup 1.0000x reference)
//
#include <hip/hip_runtime.h>

// SimpleGRU scan: B=2048 seqs, T=2048 steps, H=32, O=2, fp32 backbone.
// Round-11: 12-chain dot interleave (latency-spacing fix) on R10b's
// register-only allgather.
// R10b post-mortem: VALUBusy 88% x 498cyc = 438 "busy" >> true issue (~220
// cyc: dot2 is FULL-RATE 2cyc per ISA spec -- the session's fitted "4-6cyc"
// was dependency stall, not issue). With 6 chains, a chain's next dot comes
// 6 instrs = 12 cyc later, but dot2 dependent latency ~18-24 cyc -> ~6 cyc
// stall per dot ~= 280 cyc/step. Fix: 12 chains (4/gate) -> spacing 24 cyc.
// Retro-fits R8 (533 = stalls+LDS), R9 (+61: 16cyc spacing + reductions
// between clusters), R10b (-35: LDS gone, stalls remained).
// Also this round:
//  * x removed from dot seeds: xv*w_ih folded into FINAL reduction, so no
//    dot chain waits on the LDS x-read (chain-A seeds are pure biases).
//  * DPP butterfly built just-in-time in consumption order (4 P-regs per
//    12-dot group, built one group ahead).
//  * x_s interleaved [buf][step][group] (4B group stride -> different
//    banks; kills R10b's 2.2M 2-way conflicts from 256B stride).
// Kept: permlane32_swap builtin + orientation probe, butterfly scramble
// M[q] folded into weight packing, pre-scaled weights (-log2e / +2log2e),
// single-fma tail h' = fma(2z-2, ti, 1 + z*(h-1)).
// Model: issue ~230 + head/tail latency ~80 => ~300-360 cyc => 260-310 us.

typedef _Float16 f16x2 __attribute__((ext_vector_type(2)));

__device__ __forceinline__ float fdot2(int a, int b, float c) {
    return __builtin_amdgcn_fdot2(__builtin_bit_cast(f16x2, a),
                                  __builtin_bit_cast(f16x2, b), c, false);
}

__device__ __forceinline__ int pack_pair(float a, float b) {
    f16x2 p;
    p.x = (_Float16)a;
    p.y = (_Float16)b;
    return __builtin_bit_cast(int, p);
}

template<int CTRL>
__device__ __forceinline__ int dppmov(int src) {
    return __builtin_amdgcn_update_dpp(0, src, CTRL, 0xF, 0xF, true);
}

__global__ __launch_bounds__(64, 1)
void gru_scan_kernel(const float* __restrict__ x,      // [B,T]
                     const float* __restrict__ w_ih,   // [96,1]
                     const float* __restrict__ w_hh,   // [96,32]
                     const float* __restrict__ b_ih,   // [96]
                     const float* __restrict__ b_hh,   // [96]
                     const float* __restrict__ head_w, // [2,32]
                     const float* __restrict__ head_b, // [2]
                     float* __restrict__ out,          // [B,2]
                     int T)
{
    const int l  = (int)threadIdx.x;
    const int gg = (l >> 4) & 1;                  // batch slot within wave
    const int m  = (l & 15) + ((l >> 5) << 4);    // local gate/hidden row 0..31
    const int b  = (int)blockIdx.x * 2 + gg;

    __shared__ float hf_s[2][32];                 // fp32 h for head
    __shared__ __align__(8) float x_s[2][32][2];  // [buf][step][group]

    // ---- orientation probe: which output of permlane32_swap holds the
    // low-half broadcast? (wave-uniform; folds into weight packing) ----
    bool lowfirst;
    {
        auto pr = __builtin_amdgcn_permlane32_swap((unsigned)l, (unsigned)l,
                                                   false, false);
        lowfirst = ((int)pr[0] == (l & 31));
    }

    const float NL2E  = -1.44269504088896f;  // -log2(e): sigmoid fold
    const float P2L2E =  2.88539008177793f;  // +2*log2(e): tanh fold

    // butterfly gather order: P[q] holds pair c0 ^ M[q]
    constexpr int M[16] = {0,1,2,3,7,6,5,4,15,14,13,12,8,9,10,11};
    const int c0 = l & 15;

    // ---- per-lane weights, packed to match the gather: pair q = columns
    // (cc, cc+16), cc = c0 ^ M[q], low/high per probe. Pre-scaled. ----
    int wR[16], wZ[16], wN[16];
    {
        const float* pR = w_hh + (     m) * 32;
        const float* pZ = w_hh + (32 + m) * 32;
        const float* pN = w_hh + (64 + m) * 32;
#pragma unroll
        for (int q = 0; q < 16; ++q) {
            const int cc  = c0 ^ M[q];
            const int clo = lowfirst ? cc      : cc + 16;
            const int chi = lowfirst ? cc + 16 : cc;
            wR[q] = pack_pair(NL2E  * pR[clo], NL2E  * pR[chi]);
            wZ[q] = pack_pair(NL2E  * pZ[clo], NL2E  * pZ[chi]);
            wN[q] = pack_pair(P2L2E * pN[clo], P2L2E * pN[chi]);
        }
    }
#pragma unroll
    for (int q = 0; q < 16; ++q) {
        asm volatile("" : "+v"(wR[q]), "+v"(wZ[q]), "+v"(wN[q]));
    }

    // x-path seeds, same pre-scales (all fp32)
    const float wihr = NL2E  * w_ih[m];
    const float wihz = NL2E  * w_ih[32 + m];
    const float wihn = P2L2E * w_ih[64 + m];
    const float br   = NL2E  * (b_ih[m]      + b_hh[m]);
    const float bz   = NL2E  * (b_ih[32 + m] + b_hh[32 + m]);
    const float bni  = P2L2E * b_ih[64 + m];
    const float bnh  = P2L2E * b_hh[64 + m];

    const float* xrow   = x + (size_t)b * (size_t)T;
    const int    nchunk = T >> 5;   // 32-step chunks (T=2048 -> 64)

    float h = 0.0f;
    x_s[0][m][gg] = xrow[m];
    float xnext  = (nchunk > 1) ? xrow[32 + m] : 0.0f;
    __builtin_amdgcn_wave_barrier();

    for (int c = 0; c < nchunk; ++c) {
        const int buf = c & 1;
        const float* xs = &x_s[buf][0][gg];      // stride-2 floats per step
#pragma unroll 4
        for (int s = 0; s < 32; ++s) {
            const float xv  = xs[2 * s];         // hidden: only used in tail
            const float hm1 = h - 1.0f;          // off-path

            // ---- register allgather of h (f16): swap + JIT DPP butterfly
            // built in consumption order, one 4-reg group per 12-dot block.
            const unsigned hf = (unsigned)__builtin_bit_cast(unsigned short,
                                                             (_Float16)h);
            auto sw = __builtin_amdgcn_permlane32_swap(hf, hf, false, false);
            const int o0 = (int)sw[0];
            const int o1 = (int)sw[1];
            const int P0  = (o1 << 16) | o0;     // c0
            const int P4  = dppmov<0x141>(P0);   // c0^7
            const int P8  = dppmov<0x140>(P0);   // c0^15
            const int P12 = dppmov<0x140>(P4);   // c0^8

            // 12 chains: {r,z,n} x {A,B,C,D}; chain X uses pairs 4X..4X+3.
            // Spacing: a chain's dependent dot re-issues 12 instrs (~24cyc)
            // later >= dot2 latency -> no stall. Seeds: pure biases (xv
            // folded into the final reduction, not the dot chains).
            float rA = fdot2(P0,  wR[ 0], br);
            float zA = fdot2(P0,  wZ[ 0], bz);
            float nA = fdot2(P0,  wN[ 0], bnh);
            float rB = fdot2(P4,  wR[ 4], 0.0f);
            float zB = fdot2(P4,  wZ[ 4], 0.0f);
            float nB = fdot2(P4,  wN[ 4], 0.0f);
            float rC = fdot2(P8,  wR[ 8], 0.0f);
            float zC = fdot2(P8,  wZ[ 8], 0.0f);
            float nC = fdot2(P8,  wN[ 8], 0.0f);
            float rD = fdot2(P12, wR[12], 0.0f);
            float zD = fdot2(P12, wZ[12], 0.0f);
            float nD = fdot2(P12, wN[12], 0.0f);

            const int P1  = dppmov<0xB1 >(P0);   // c0^1
            const int P5  = dppmov<0x141>(P1);   // c0^6
            const int P9  = dppmov<0x140>(P1);   // c0^14
            const int P13 = dppmov<0x140>(P5);   // c0^9
            rA = fdot2(P1,  wR[ 1], rA);
            zA = fdot2(P1,  wZ[ 1], zA);
            nA = fdot2(P1,  wN[ 1], nA);
            rB = fdot2(P5,  wR[ 5], rB);
            zB = fdot2(P5,  wZ[ 5], zB);
            nB = fdot2(P5,  wN[ 5], nB);
            rC = fdot2(P9,  wR[ 9], rC);
            zC = fdot2(P9,  wZ[ 9], zC);
            nC = fdot2(P9,  wN[ 9], nC);
            rD = fdot2(P13, wR[13], rD);
            zD = fdot2(P13, wZ[13], zD);
            nD = fdot2(P13, wN[13], nD);

            const int P2  = dppmov<0x4E >(P0);   // c0^2
            const int P6  = dppmov<0x141>(P2);   // c0^5
            const int P10 = dppmov<0x140>(P2);   // c0^13
            const int P14 = dppmov<0x140>(P6);   // c0^10
            rA = fdot2(P2,  wR[ 2], rA);
            zA = fdot2(P2,  wZ[ 2], zA);
            nA = fdot2(P2,  wN[ 2], nA);
            rB = fdot2(P6,  wR[ 6], rB);
            zB = fdot2(P6,  wZ[ 6], zB);
            nB = fdot2(P6,  wN[ 6], nB);
            rC = fdot2(P10, wR[10], rC);
            zC = fdot2(P10, wZ[10], zC);
            nC = fdot2(P10, wN[10], nC);
            rD = fdot2(P14, wR[14], rD);
            zD = fdot2(P14, wZ[14], zD);
            nD = fdot2(P14, wN[14], nD);

            const int P3  = dppmov<0x4E >(P1);   // c0^3
            const int P7  = dppmov<0x141>(P3);   // c0^4
            const int P11 = dppmov<0x140>(P3);   // c0^12
            const int P15 = dppmov<0x140>(P7);   // c0^11
            rA = fdot2(P3,  wR[ 3], rA);
            zA = fdot2(P3,  wZ[ 3], zA);
            nA = fdot2(P3,  wN[ 3], nA);
            rB = fdot2(P7,  wR[ 7], rB);
            zB = fdot2(P7,  wZ[ 7], zB);
            nB = fdot2(P7,  wN[ 7], nB);
            rC = fdot2(P11, wR[11], rC);
            zC = fdot2(P11, wZ[11], zC);
            nC = fdot2(P11, wN[11], nC);
            rD = fdot2(P15, wR[15], rD);
            zD = fdot2(P15, wZ[15], zD);
            nD = fdot2(P15, wN[15], nD);

            // ---- folded tail: xv joins here (never on the dot chains) ----
            const float rp = fmaf(xv, wihr, (rA + rB) + (rC + rD));
            const float zp = fmaf(xv, wihz, (zA + zB) + (zC + zD));
            const float np = (nA + nB) + (nC + nD);
            const float er = __builtin_amdgcn_exp2f(rp);   // pre-scaled
            const float ez = __builtin_amdgcn_exp2f(zp);
            const float r  = __builtin_amdgcn_rcpf(1.0f + er);
            const float z  = __builtin_amdgcn_rcpf(1.0f + ez);
            const float m2omz = fmaf(2.0f, z, -2.0f);      // 2z-2
            const float ohz   = fmaf(z, hm1, 1.0f);        // 1 - z + z*h
            const float u  = fmaf(r, np, fmaf(xv, wihn, bni));
            const float et = __builtin_amdgcn_exp2f(u);    // e^{2*u_orig}
            const float ti = __builtin_amdgcn_rcpf(1.0f + et);
            h = fmaf(m2omz, ti, ohz);    // (1-z)*tanh + z*h, tanh = 1-2ti
        }
        if (c + 1 < nchunk) {
            x_s[1 - buf][m][gg] = xnext;             // stage next chunk
            if (c + 2 < nchunk) xnext = xrow[(c + 2) * 32 + m];
            __builtin_amdgcn_wave_barrier();
        }
    }

    // ---- head: out[b,o] = head_b[o] + sum_k h[k]*head_w[o,k] (fp32 h) ----
    hf_s[gg][m] = h;
    __builtin_amdgcn_wave_barrier();
    if (l < 4) {
        const int g2 = l >> 1, o = l & 1;
        float acc = head_b[o];
        const float* hw = head_w + o * 32;
#pragma unroll
        for (int k = 0; k < 32; ++k) acc = fmaf(hf_s[g2][k], hw[k], acc);
        out[((int)blockIdx.x * 2 + g2) * 2 + o] = acc;
    }
}

extern "C" void kernel_launch(void* const* d_in, const int* in_sizes, int n_in,
                              void* d_out, int out_size, void* d_ws, size_t ws_size,
                              hipStream_t stream) {
    const float* x      = (const float*)d_in[0];
    const float* w_ih   = (const float*)d_in[1];
    const float* w_hh   = (const float*)d_in[2];
    const float* b_ih   = (const float*)d_in[3];
    const float* b_hh   = (const float*)d_in[4];
    const float* head_w = (const float*)d_in[5];
    const float* head_b = (const float*)d_in[6];
    float* out = (float*)d_out;

    const int B = out_size / 2;          // O = 2
    const int T = in_sizes[0] / B;       // x is [B,T]

    dim3 grid(B / 2), block(64);
    hipLaunchKernelGGL(gru_scan_kernel, grid, block, 0, stream,
                       x, w_ih, w_hh, b_ih, b_hh, head_w, head_b, out, T);
}